// Round 6
// baseline (276.710 us; speedup 1.0000x reference)
//
#include <hip/hip_runtime.h>
#include <hip/hip_bf16.h>
#include <math.h>
#include <stdint.h>

// ArcFace loss via MX-fp8 (e4m3, identity scales) MFMA GEMM + fused
// fixed-max softmax. B=2048, D=512, C=50000. Output: scalar mean NLL (f32).
//
// R11:
//  - k_gemm: halved LDS redundancy + halved barriers. Waves now hold 64
//    A-rows (2 row-halves x 2 col-halves across 4 waves); strip = 64 cols
//    (2 x 32KB dbuf, 7 barriers/chunk vs 14). LDS-issue pipe drops from
//    ~31us (was > MFMA 22.5us floor) to ~15.5us -> MFMA becomes dominant.
//    Partials now at half-chunk granularity (224/row) since the two
//    col-half waves can't cheaply combine.
//  - k_fin absorbs k_sum via last-block ticket (threadfence + device atomics):
//    4 launches -> 3.
//  - k_prep byte-identical to R10 (control; still invisible in top-5 -> if
//    new gemm < prep, prep surfaces with counters next round).
//
// Numerics: logits = 30*cos in [-30,30] -> fixed max 30, plain sums:
//   lse = 30 + log(sum_c exp(l_c - 30)); label logit recomputed exactly in
//   fp32 at finalize, so fp8 error only perturbs the softmax denominator.

#define B_ROWS    2048
#define D_DIM     512
#define C_CLASSES 50000
#define C_PAD     50176            // 112 * 448
#define NCHUNK    112              // 448-wide chunks
#define CH_COLS   448
#define NSTRIP    7                // 64-col strips per chunk
#define NPART     224              // half-chunk partials per row (112 * 2)
#define ARC_MARGIN 0.3f
#define ARC_SCALE  30.0f
#define ARC_EPS    1e-12f
#define K_LOG2E_S  43.2808512f     // 30 * log2(e)

// workspace layout (bytes)
#define OFF_WQ    0u               // 50176*512 = 25,690,112
#define OFF_EMBQ  25690112u        // 2048*512  =  1,048,576
#define OFF_WINV  26738688u        // 50000*4   =    200,000
#define OFF_EINV  26938688u        // 2048*4    =      8,192
#define OFF_PART  26946880u        // 2048*224*4 = 1,835,008
#define OFF_FINP  28781888u        // 256*4     =      1,024
#define OFF_TICK  28782912u        // 4                        -> total ~28.8 MB

typedef __attribute__((ext_vector_type(8))) int   i32x8;
typedef __attribute__((ext_vector_type(4))) int   i32x4;
typedef __attribute__((ext_vector_type(4))) float f32x4;

typedef __attribute__((address_space(1))) const unsigned int g_u32;
typedef __attribute__((address_space(3))) unsigned int       l_u32;

__device__ __forceinline__ void gload_lds16(const void* g, void* l) {
    // dest is wave-uniform LDS base; HW writes lane i at base + i*16
    g_u32* gp = (g_u32*)(uintptr_t)g;
    l_u32* lp = (l_u32*)(uintptr_t)l;
    __builtin_amdgcn_global_load_lds(gp, lp, 16, 0, 0);
}

// ---------------- prep: rows -> normalized e4m3 + inverse norms ----------------
// One wave per 8 consecutive rows; all 16 row-loads issued before any use
// (256 B/lane outstanding). Row space: [0,C_PAD) = weight (pad rows
// zero-filled), [C_PAD, C_PAD+B) = embeddings. All segments are multiples of
// 8 rows (50000, 176, 2048), so an 8-row group never straddles segments.
__global__ __launch_bounds__(256) void k_prep(const float* __restrict__ emb,
                                              const float* __restrict__ weight,
                                              uint8_t* __restrict__ embq,
                                              uint8_t* __restrict__ wq,
                                              float* __restrict__ einv,
                                              float* __restrict__ winv,
                                              unsigned int* __restrict__ ticket) {
    if (blockIdx.x == 0 && threadIdx.x == 0) *ticket = 0u;  // for k_fin last-block
    int wave = blockIdx.x * (blockDim.x >> 6) + (threadIdx.x >> 6);
    int lane = threadIdx.x & 63;
    int g0   = wave << 3;              // first of 8 consecutive rows

    const float* src;
    uint8_t* dst;
    float* invout;
    if (g0 >= C_PAD) {                 // embedding rows
        int row = g0 - C_PAD;
        src = emb + (size_t)row * D_DIM;
        dst = embq + (size_t)row * D_DIM;
        invout = einv + row;
    } else if (g0 >= C_CLASSES) {      // zero-fill pad classes
        int2 z = make_int2(0, 0);
        #pragma unroll
        for (int r = 0; r < 8; ++r)
            *(int2*)(wq + (size_t)(g0 + r) * D_DIM + lane * 8) = z;
        return;
    } else {                           // weight rows
        src = weight + (size_t)g0 * D_DIM;
        dst = wq + (size_t)g0 * D_DIM;
        invout = winv + g0;
    }

    // issue all 16 loads before any use: 256 B/lane outstanding
    const float4* r4 = (const float4*)src;
    float4 v[16];
    #pragma unroll
    for (int r = 0; r < 8; ++r) {
        v[2 * r]     = r4[r * 128 + lane * 2];
        v[2 * r + 1] = r4[r * 128 + lane * 2 + 1];
    }

    #pragma unroll
    for (int r = 0; r < 8; ++r) {
        float4 v0 = v[2 * r], v1 = v[2 * r + 1];
        float s = v0.x*v0.x + v0.y*v0.y + v0.z*v0.z + v0.w*v0.w
                + v1.x*v1.x + v1.y*v1.y + v1.z*v1.z + v1.w*v1.w;
        #pragma unroll
        for (int off = 32; off; off >>= 1) s += __shfl_xor(s, off);
        float rn = 1.0f / fmaxf(sqrtf(s), ARC_EPS);
        if (lane == 0) invout[r] = rn;
        int p0 = __builtin_amdgcn_cvt_pk_fp8_f32(v0.x * rn, v0.y * rn, 0, false);
        p0     = __builtin_amdgcn_cvt_pk_fp8_f32(v0.z * rn, v0.w * rn, p0, true);
        int p1 = __builtin_amdgcn_cvt_pk_fp8_f32(v1.x * rn, v1.y * rn, 0, false);
        p1     = __builtin_amdgcn_cvt_pk_fp8_f32(v1.z * rn, v1.w * rn, p1, true);
        *(int2*)(dst + (size_t)r * D_DIM + lane * 8) = make_int2(p0, p1);
    }
}

struct TrueT  { static constexpr bool value = true;  };
struct FalseT { static constexpr bool value = false; };

// ---------------- GEMM (MX-fp8, identity scales) + fused exp-sum -------------
// Block: 4 waves = 2 row-halves x 2 col-halves over a 128-row x 448-col tile.
// Wave holds its 64 A-rows' full K=512 in regs (16 x i32x8; AGPR-eligible).
// B consumed in 64-col strips staged in LDS (2 x 32KB dbuf, one barrier per
// strip, 7 strips). Each wave reads only its 32-col half of the strip ->
// per-block LDS read volume halves vs R10 (was the dominant pipe at ~31us).
// LDS cell layout per 16-col group cg: [kc 0..31][col 0..15] 16B cells
// (gload_lds lane order == layout; ds_read_b128 pattern measured 0 conflicts).
__global__ __launch_bounds__(256) void k_gemm(const uint8_t* __restrict__ embq,
                                              const uint8_t* __restrict__ wq,
                                              float* __restrict__ partials) {
    __shared__ __align__(16) uint8_t Bs[2][32768];

    const int tid  = threadIdx.x;
    const int w    = tid >> 6;         // wave 0..3
    const int lane = tid & 63;
    const int c    = lane & 15;        // row/col within 16-group
    const int q    = lane >> 4;        // k-slice quad
    const int rh   = w >> 1;           // row-half  (64 rows)
    const int ch   = w & 1;            // col-half  (32 cols of each strip)

    // XCD-affinity: consecutive ids round-robin XCDs; XCD x owns chunks
    // [x*14, x*14+14) for ALL row-blocks -> 3.2MB B slice stays in its L2.
    const int id  = blockIdx.x;        // 0..1791
    const int xcd = id & 7;
    const int s   = id >> 3;           // 0..223
    const int ci  = s % 14;
    const int rb  = s / 14;            // 0..15
    const int chunk = xcd * 14 + ci;
    const int b0 = rb * 128;
    const int n0 = chunk * CH_COLS;

    // ---- A fragments: wave's 64 rows (4 x 16-row groups), full K=512 ----
    const int r0 = b0 + rh * 64;
    i32x8 af[4][4];                    // [row-group][kt]
    #pragma unroll
    for (int rg = 0; rg < 4; ++rg) {
        const uint8_t* pr = embq + (size_t)(r0 + rg * 16 + c) * D_DIM;
        #pragma unroll
        for (int kt = 0; kt < 4; ++kt) {
            const uint8_t* pa = pr + kt * 128 + q * 32;
            i32x4 lo = *(const i32x4*)pa;
            i32x4 hi = *(const i32x4*)(pa + 16);
            af[rg][kt] = (i32x8){lo[0], lo[1], lo[2], lo[3],
                                 hi[0], hi[1], hi[2], hi[3]};
        }
    }

    // ---- staging: one 64-col strip = 32KB; 32 gload_lds16 / block ----
    auto stage = [&](uint8_t* dst, int st) {
        const uint8_t* base = wq + (size_t)(n0 + st * 64) * D_DIM;
        #pragma unroll
        for (int t = 0; t < 8; ++t) {
            const int p  = w * 8 + t;          // 0..31
            const int cg = p >> 3;             // 0..3 : 16-col group
            const int h  = p & 7;              // 0..7 : kc block of 4
            gload_lds16(base + (size_t)(cg * 16 + c) * D_DIM + (h * 4 + q) * 16,
                        dst + cg * 8192 + h * 1024);
        }
    };

    f32x4 rs[4];
    #pragma unroll
    for (int rg = 0; rg < 4; ++rg) rs[rg] = (f32x4){0.f, 0.f, 0.f, 0.f};

    // per strip: wave reads its 2 col-groups; per (cb,kt): 2 ds_read_b128
    // feed 4 MFMAs (one per row-group); then exp2-accumulate. No C-tile.
    auto compute = [&](const uint8_t* buf, int st, auto maskTag) {
        constexpr bool MASK = decltype(maskTag)::value;
        #pragma unroll
        for (int cb = 0; cb < 2; ++cb) {
            const int cg = ch * 2 + cb;        // 0..3 within strip
            f32x4 a0 = (f32x4){0.f, 0.f, 0.f, 0.f};
            f32x4 a1 = (f32x4){0.f, 0.f, 0.f, 0.f};
            f32x4 a2 = (f32x4){0.f, 0.f, 0.f, 0.f};
            f32x4 a3 = (f32x4){0.f, 0.f, 0.f, 0.f};
            #pragma unroll
            for (int kt = 0; kt < 4; ++kt) {
                const uint8_t* p = buf + cg * 8192 + (kt * 8 + 2 * q) * 256 + c * 16;
                i32x4 lo = *(const i32x4*)p;
                i32x4 hi = *(const i32x4*)(p + 256);
                i32x8 bf = (i32x8){lo[0], lo[1], lo[2], lo[3],
                                   hi[0], hi[1], hi[2], hi[3]};
                a0 = __builtin_amdgcn_mfma_scale_f32_16x16x128_f8f6f4(
                        af[0][kt], bf, a0, 0, 0, 0, 127, 0, 127);
                a1 = __builtin_amdgcn_mfma_scale_f32_16x16x128_f8f6f4(
                        af[1][kt], bf, a1, 0, 0, 0, 127, 0, 127);
                a2 = __builtin_amdgcn_mfma_scale_f32_16x16x128_f8f6f4(
                        af[2][kt], bf, a2, 0, 0, 0, 127, 0, 127);
                a3 = __builtin_amdgcn_mfma_scale_f32_16x16x128_f8f6f4(
                        af[3][kt], bf, a3, 0, 0, 0, 127, 0, 127);
            }
            bool pad = false;
            if (MASK) pad = (n0 + st * 64 + cg * 16 + c) >= C_CLASSES;
            #pragma unroll
            for (int reg = 0; reg < 4; ++reg) {
                float t0 = __builtin_amdgcn_exp2f(fmaf(a0[reg], K_LOG2E_S, -K_LOG2E_S));
                float t1 = __builtin_amdgcn_exp2f(fmaf(a1[reg], K_LOG2E_S, -K_LOG2E_S));
                float t2 = __builtin_amdgcn_exp2f(fmaf(a2[reg], K_LOG2E_S, -K_LOG2E_S));
                float t3 = __builtin_amdgcn_exp2f(fmaf(a3[reg], K_LOG2E_S, -K_LOG2E_S));
                if (MASK && pad) { t0 = 0.f; t1 = 0.f; t2 = 0.f; t3 = 0.f; }
                rs[0][reg] += t0;
                rs[1][reg] += t1;
                rs[2][reg] += t2;
                rs[3][reg] += t3;
            }
        }
    };

    auto run = [&](auto maskTag) {
        stage(&Bs[0][0], 0);
        __syncthreads();                        // A frags + strip 0 resident
        #pragma unroll 1
        for (int st = 0; st < NSTRIP; st += 2) {
            if (st + 1 < NSTRIP) stage(&Bs[1][0], st + 1);
            compute(&Bs[0][0], st, maskTag);
            __syncthreads();                    // drains stage -> Bs[1] ready
            if (st + 2 < NSTRIP) stage(&Bs[0][0], st + 2);
            if (st + 1 < NSTRIP) {
                compute(&Bs[1][0], st + 1, maskTag);
                __syncthreads();
            }
        }
    };
    if (chunk == NCHUNK - 1) run(TrueT{}); else run(FalseT{});

    // wave-level col reduction: sum rs over the 16 col-lanes.
    // Waves ch=0/1 cover different col-halves -> partials at half-chunk
    // granularity (NPART=224 per row), combined in k_fin.
    #pragma unroll
    for (int off = 1; off < 16; off <<= 1)
        #pragma unroll
        for (int rg = 0; rg < 4; ++rg)
            #pragma unroll
            for (int reg = 0; reg < 4; ++reg)
                rs[rg][reg] += __shfl_xor(rs[rg][reg], off);

    if (c == 0) {                               // lanes 0,16,32,48
        const int pcol = chunk * 2 + ch;
        #pragma unroll
        for (int rg = 0; rg < 4; ++rg)
            #pragma unroll
            for (int reg = 0; reg < 4; ++reg)
                partials[(size_t)(r0 + rg * 16 + q * 4 + reg) * NPART + pcol]
                    = rs[rg][reg];
    }
}

// -------- finalize: exact label logit + partial sum -> mean NLL (fused sum) ---
// 256 blocks x 8 rows; wave handles 2 rows. Block partial -> finpart[bid];
// last-arriving block (device-scope ticket) reduces finpart -> out. No k_sum.
__global__ __launch_bounds__(256) void k_fin(const float* __restrict__ emb,
                                             const float* __restrict__ weight,
                                             const float* __restrict__ einv,
                                             const float* __restrict__ winv,
                                             const int* __restrict__ labels,
                                             const float* __restrict__ partials,
                                             float* __restrict__ finpart,
                                             unsigned int* __restrict__ ticket,
                                             float* __restrict__ out) {
    __shared__ float sm[8];
    __shared__ int is_last;
    int w    = threadIdx.x >> 6;       // 0..3
    int lane = threadIdx.x & 63;
    int b0   = blockIdx.x * 8 + w * 2; // wave's two rows: b0, b0+1

    int lab[2] = {labels[b0], labels[b0 + 1]};
    float4 e0[2], e1[2], w0[2], w1[2];
    float p[2][4];
    #pragma unroll
    for (int r = 0; r < 2; ++r) {      // issue all loads for both rows
        const float4* e  = (const float4*)(emb + (size_t)(b0 + r) * D_DIM);
        const float4* wt = (const float4*)(weight + (size_t)lab[r] * D_DIM);
        e0[r] = e[lane];  e1[r] = e[lane + 64];
        w0[r] = wt[lane]; w1[r] = wt[lane + 64];
        #pragma unroll
        for (int t = 0; t < 4; ++t) {
            int idx = lane + t * 64;
            p[r][t] = (idx < NPART)
                    ? partials[(size_t)(b0 + r) * NPART + idx] : 0.f;
        }
    }

    #pragma unroll
    for (int r = 0; r < 2; ++r) {
        float dot = e0[r].x*w0[r].x + e0[r].y*w0[r].y + e0[r].z*w0[r].z + e0[r].w*w0[r].w
                  + e1[r].x*w1[r].x + e1[r].y*w1[r].y + e1[r].z*w1[r].z + e1[r].w*w1[r].w;
        float ls = p[r][0] + p[r][1] + p[r][2] + p[r][3];
        #pragma unroll
        for (int off = 32; off; off >>= 1) {
            dot += __shfl_xor(dot, off);
            ls  += __shfl_xor(ls, off);
        }
        if (lane == 0) {
            int b = b0 + r;
            float cosv   = dot * einv[b] * winv[lab[r]];
            float l_orig = ARC_SCALE * cosv;
            float l_adj  = ARC_SCALE * (cosv - ARC_MARGIN);
            // swap (fp8-accumulated) label term for exact margin-adjusted one
            float s_adj = ls - __expf(l_orig - ARC_SCALE) + __expf(l_adj - ARC_SCALE);
            sm[w * 2 + r] = ARC_SCALE + logf(s_adj) - l_adj;
        }
    }
    __syncthreads();
    if (threadIdx.x == 0) {
        float t = 0.f;
        #pragma unroll
        for (int i = 0; i < 8; ++i) t += sm[i];
        finpart[blockIdx.x] = t;
        __threadfence();                               // publish before ticket
        unsigned int old = atomicAdd(ticket, 1u);      // device scope
        is_last = (old == gridDim.x - 1) ? 1 : 0;
    }
    __syncthreads();
    if (is_last) {
        __threadfence();                               // acquire finpart
        volatile const float* fp = finpart;
        float v = fp[threadIdx.x];
        #pragma unroll
        for (int off = 32; off; off >>= 1) v += __shfl_xor(v, off);
        if (lane == 0) sm[w] = v;
        __syncthreads();
        if (threadIdx.x == 0)
            out[0] = (sm[0] + sm[1] + sm[2] + sm[3]) * (1.0f / (float)B_ROWS);
    }
}

extern "C" void kernel_launch(void* const* d_in, const int* in_sizes, int n_in,
                              void* d_out, int out_size, void* d_ws, size_t ws_size,
                              hipStream_t stream) {
    const float* emb    = (const float*)d_in[0];   // (2048, 512) f32
    const int*   labels = (const int*)d_in[1];     // (2048,)
    const float* weight = (const float*)d_in[2];   // (50000, 512) f32
    float* out = (float*)d_out;

    char* ws = (char*)d_ws;
    uint8_t* wq    = (uint8_t*)(ws + OFF_WQ);
    uint8_t* embq  = (uint8_t*)(ws + OFF_EMBQ);
    float* winv     = (float*)(ws + OFF_WINV);
    float* einv     = (float*)(ws + OFF_EINV);
    float* partials = (float*)(ws + OFF_PART);
    float* finpart  = (float*)(ws + OFF_FINP);
    unsigned int* ticket = (unsigned int*)(ws + OFF_TICK);

    // (C_PAD + B_ROWS) rows, 8 rows/wave, 4 waves/block
    k_prep<<<(C_PAD + B_ROWS) / 32, 256, 0, stream>>>(emb, weight, embq, wq,
                                                      einv, winv, ticket);

    // 8 XCD x (14 chunks x 16 row-blocks) = 1792 blocks, no dead blocks
    k_gemm<<<1792, 256, 0, stream>>>(embq, wq, partials);

    k_fin<<<B_ROWS / 8, 256, 0, stream>>>(emb, weight, einv, winv, labels,
                                          partials, finpart, ticket, out);
}

// Round 7
// 244.029 us; speedup vs baseline: 1.1339x; 1.1339x over previous
//
#include <hip/hip_runtime.h>
#include <hip/hip_bf16.h>
#include <math.h>
#include <stdint.h>

// ArcFace loss via MX-fp8 (e4m3, identity scales) MFMA GEMM + fused
// fixed-max softmax. B=2048, D=512, C=50000. Output: scalar mean NLL (f32).
//
// R12: DIAGNOSTIC ROUND. R11's 64-col-strip gemm regressed (LDS 64KB +
//      VGPR 132 -> occupancy 19->11%, MfmaUtil 28->18) and is reverted to
//      the R10 form (75us measured). The ~159us non-gemm residual has now
//      survived three structurally different prep/fin rewrites -- it cannot
//      be modeled blind. This round splits k_gemm into TWO half-grid
//      dispatches (~40us each) so the rocprof top-5 threshold drops from
//      ~75us to ~40us: any kernel above 40us surfaces with full counters.
//      If none surfaces, the residual is inter-dispatch overhead -> merge
//      kernels next. Cost of instrument: ~5us tail imbalance.
//
// Numerics: logits = 30*cos in [-30,30] -> fixed max 30, plain sums:
//   lse = 30 + log(sum_c exp(l_c - 30)); label logit recomputed exactly in
//   fp32 at finalize, so fp8 error only perturbs the softmax denominator.

#define B_ROWS    2048
#define D_DIM     512
#define C_CLASSES 50000
#define C_PAD     50176            // 112 * 448
#define NCHUNK    112              // 448-wide chunks
#define CH_COLS   448
#define NSTRIP    14               // 32-col strips per chunk
#define ARC_MARGIN 0.3f
#define ARC_SCALE  30.0f
#define ARC_EPS    1e-12f
#define K_LOG2E_S  43.2808512f     // 30 * log2(e)

// workspace layout (bytes)
#define OFF_WQ    0u               // 50176*512 = 25,690,112
#define OFF_EMBQ  25690112u        // 2048*512  =  1,048,576
#define OFF_WINV  26738688u        // 50000*4   =    200,000
#define OFF_EINV  26938688u        // 2048*4    =      8,192
#define OFF_PART  26946880u        // 2048*112*4 =   917,504
#define OFF_FINP  27864384u        // 256*4     =      1,024  -> total ~27.9 MB

typedef __attribute__((ext_vector_type(8))) int   i32x8;
typedef __attribute__((ext_vector_type(4))) int   i32x4;
typedef __attribute__((ext_vector_type(4))) float f32x4;

typedef __attribute__((address_space(1))) const unsigned int g_u32;
typedef __attribute__((address_space(3))) unsigned int       l_u32;

__device__ __forceinline__ void gload_lds16(const void* g, void* l) {
    // dest is wave-uniform LDS base; HW writes lane i at base + i*16
    g_u32* gp = (g_u32*)(uintptr_t)g;
    l_u32* lp = (l_u32*)(uintptr_t)l;
    __builtin_amdgcn_global_load_lds(gp, lp, 16, 0, 0);
}

// ---------------- prep: rows -> normalized e4m3 + inverse norms ----------------
// One wave per 8 consecutive rows; all 16 row-loads issued before any use
// (256 B/lane outstanding). Row space: [0,C_PAD) = weight (pad rows
// zero-filled), [C_PAD, C_PAD+B) = embeddings. All segments are multiples of
// 8 rows (50000, 176, 2048), so an 8-row group never straddles segments.
// [byte-identical to R10]
__global__ __launch_bounds__(256) void k_prep(const float* __restrict__ emb,
                                              const float* __restrict__ weight,
                                              uint8_t* __restrict__ embq,
                                              uint8_t* __restrict__ wq,
                                              float* __restrict__ einv,
                                              float* __restrict__ winv,
                                              float* __restrict__ out) {
    int wave = blockIdx.x * (blockDim.x >> 6) + (threadIdx.x >> 6);
    int lane = threadIdx.x & 63;
    int g0   = wave << 3;              // first of 8 consecutive rows

    const float* src;
    uint8_t* dst;
    float* invout;
    if (g0 >= C_PAD) {                 // embedding rows
        int row = g0 - C_PAD;
        src = emb + (size_t)row * D_DIM;
        dst = embq + (size_t)row * D_DIM;
        invout = einv + row;
    } else if (g0 >= C_CLASSES) {      // zero-fill pad classes
        int2 z = make_int2(0, 0);
        #pragma unroll
        for (int r = 0; r < 8; ++r)
            *(int2*)(wq + (size_t)(g0 + r) * D_DIM + lane * 8) = z;
        return;
    } else {                           // weight rows
        src = weight + (size_t)g0 * D_DIM;
        dst = wq + (size_t)g0 * D_DIM;
        invout = winv + g0;
    }

    // issue all 16 loads before any use: 256 B/lane outstanding
    const float4* r4 = (const float4*)src;
    float4 v[16];
    #pragma unroll
    for (int r = 0; r < 8; ++r) {
        v[2 * r]     = r4[r * 128 + lane * 2];
        v[2 * r + 1] = r4[r * 128 + lane * 2 + 1];
    }

    #pragma unroll
    for (int r = 0; r < 8; ++r) {
        float4 v0 = v[2 * r], v1 = v[2 * r + 1];
        float s = v0.x*v0.x + v0.y*v0.y + v0.z*v0.z + v0.w*v0.w
                + v1.x*v1.x + v1.y*v1.y + v1.z*v1.z + v1.w*v1.w;
        #pragma unroll
        for (int off = 32; off; off >>= 1) s += __shfl_xor(s, off);
        float rn = 1.0f / fmaxf(sqrtf(s), ARC_EPS);
        if (lane == 0) invout[r] = rn;
        int p0 = __builtin_amdgcn_cvt_pk_fp8_f32(v0.x * rn, v0.y * rn, 0, false);
        p0     = __builtin_amdgcn_cvt_pk_fp8_f32(v0.z * rn, v0.w * rn, p0, true);
        int p1 = __builtin_amdgcn_cvt_pk_fp8_f32(v1.x * rn, v1.y * rn, 0, false);
        p1     = __builtin_amdgcn_cvt_pk_fp8_f32(v1.z * rn, v1.w * rn, p1, true);
        *(int2*)(dst + (size_t)r * D_DIM + lane * 8) = make_int2(p0, p1);
    }
}

struct TrueT  { static constexpr bool value = true;  };
struct FalseT { static constexpr bool value = false; };

// ---------------- GEMM (MX-fp8, identity scales) + fused exp-sum -------------
// [R10/R9 structure, 75us measured] Block: 4 waves x 32 rows = 128 rows;
// chunk = 448 cols = 14 strips of 32. Wave's A rows (32 x 512B) in regs.
// B strips staged in LDS (2 x 16KB dbuf). Launched as TWO half-grid
// dispatches (base = 0, 896) purely for rocprof top-5 visibility.
__global__ __launch_bounds__(256) void k_gemm(const uint8_t* __restrict__ embq,
                                              const uint8_t* __restrict__ wq,
                                              float* __restrict__ partials,
                                              int base) {
    __shared__ __align__(16) uint8_t Bs[2][16384];

    const int tid  = threadIdx.x;
    const int w    = tid >> 6;         // wave 0..3
    const int lane = tid & 63;
    const int c    = lane & 15;        // row/col within 16-group
    const int q    = lane >> 4;        // k-slice quad

    // XCD-affinity: consecutive ids round-robin XCDs; XCD x owns chunks
    // [x*14, x*14+14) for ALL row-blocks -> 3.2MB B slice stays in its L2.
    const int id  = blockIdx.x + base; // 0..1791 across the two dispatches
    const int xcd = id & 7;
    const int s   = id >> 3;           // 0..223
    const int ci  = s % 14;
    const int rb  = s / 14;            // 0..15
    const int chunk = xcd * 14 + ci;
    const int b0 = rb * 128;
    const int n0 = chunk * CH_COLS;

    // ---- A fragments: wave's 32 rows, full K=512, in registers ----
    const int r0 = b0 + w * 32;
    i32x8 afA[4], afB[4];
    #pragma unroll
    for (int kt = 0; kt < 4; ++kt) {
        const uint8_t* pa = embq + (size_t)(r0 + c) * D_DIM + kt * 128 + q * 32;
        const uint8_t* pb = embq + (size_t)(r0 + 16 + c) * D_DIM + kt * 128 + q * 32;
        i32x4 alo = *(const i32x4*)pa;
        i32x4 ahi = *(const i32x4*)(pa + 16);
        i32x4 blo = *(const i32x4*)pb;
        i32x4 bhi = *(const i32x4*)(pb + 16);
        afA[kt] = (i32x8){alo[0], alo[1], alo[2], alo[3], ahi[0], ahi[1], ahi[2], ahi[3]};
        afB[kt] = (i32x8){blo[0], blo[1], blo[2], blo[3], bhi[0], bhi[1], bhi[2], bhi[3]};
    }

    // ---- staging: one 32-col x 512B strip = 16KB; 16 gload_lds16 / block ----
    auto stage = [&](uint8_t* dst, int st) {
        const uint8_t* base_ = wq + (size_t)(n0 + st * 32) * D_DIM;
        #pragma unroll
        for (int t = 0; t < 4; ++t) {
            const int p  = w * 4 + t;          // 0..15
            const int cb = p >> 3;             // 0..1 : 16-col group
            const int h  = p & 7;              // 0..7 : kc block of 4
            gload_lds16(base_ + (size_t)(cb * 16 + c) * D_DIM + (h * 4 + q) * 16,
                        dst + cb * 8192 + h * 1024);
        }
    };

    f32x4 rs0 = (f32x4){0.f, 0.f, 0.f, 0.f};
    f32x4 rs1 = (f32x4){0.f, 0.f, 0.f, 0.f};

    // per strip: 2 col-groups x 4 kt: bf (2 x ds_read_b128) feeds 2 MFMAs
    // (row-groups A,B); then exp2-accumulate into rs. No C-tile.
    auto compute = [&](const uint8_t* buf, int st, auto maskTag) {
        constexpr bool MASK = decltype(maskTag)::value;
        #pragma unroll
        for (int cb = 0; cb < 2; ++cb) {
            f32x4 a0 = (f32x4){0.f, 0.f, 0.f, 0.f};
            f32x4 a1 = (f32x4){0.f, 0.f, 0.f, 0.f};
            #pragma unroll
            for (int kt = 0; kt < 4; ++kt) {
                const uint8_t* p = buf + cb * 8192 + (kt * 8 + 2 * q) * 256 + c * 16;
                i32x4 lo = *(const i32x4*)p;
                i32x4 hi = *(const i32x4*)(p + 256);
                i32x8 bf = (i32x8){lo[0], lo[1], lo[2], lo[3],
                                   hi[0], hi[1], hi[2], hi[3]};
                a0 = __builtin_amdgcn_mfma_scale_f32_16x16x128_f8f6f4(
                        afA[kt], bf, a0, 0, 0, 0, 127, 0, 127);
                a1 = __builtin_amdgcn_mfma_scale_f32_16x16x128_f8f6f4(
                        afB[kt], bf, a1, 0, 0, 0, 127, 0, 127);
            }
            bool pad = false;
            if (MASK) pad = (n0 + st * 32 + cb * 16 + c) >= C_CLASSES;
            #pragma unroll
            for (int reg = 0; reg < 4; ++reg) {
                float t0 = __builtin_amdgcn_exp2f(fmaf(a0[reg], K_LOG2E_S, -K_LOG2E_S));
                float t1 = __builtin_amdgcn_exp2f(fmaf(a1[reg], K_LOG2E_S, -K_LOG2E_S));
                if (MASK && pad) { t0 = 0.f; t1 = 0.f; }
                rs0[reg] += t0;
                rs1[reg] += t1;
            }
        }
    };

    auto run = [&](auto maskTag) {
        stage(&Bs[0][0], 0);
        __syncthreads();                        // A frags + strip 0 resident
        #pragma unroll 1
        for (int st = 0; st < NSTRIP; st += 2) {
            stage(&Bs[1][0], st + 1);           // issue next BEFORE compute
            compute(&Bs[0][0], st, maskTag);
            __syncthreads();                    // drains stage -> Bs[1] ready
            if (st + 2 < NSTRIP) stage(&Bs[0][0], st + 2);
            compute(&Bs[1][0], st + 1, maskTag);
            __syncthreads();
        }
    };
    if (chunk == NCHUNK - 1) run(TrueT{}); else run(FalseT{});

    // wave-level col reduction: sum rs over the 16 col-lanes
    #pragma unroll
    for (int off = 1; off < 16; off <<= 1) {
        #pragma unroll
        for (int reg = 0; reg < 4; ++reg) {
            rs0[reg] += __shfl_xor(rs0[reg], off);
            rs1[reg] += __shfl_xor(rs1[reg], off);
        }
    }
    if (c == 0) {                               // lanes 0,16,32,48
        #pragma unroll
        for (int reg = 0; reg < 4; ++reg) {
            partials[(size_t)(r0 + q * 4 + reg) * NCHUNK + chunk]      = rs0[reg];
            partials[(size_t)(r0 + 16 + q * 4 + reg) * NCHUNK + chunk] = rs1[reg];
        }
    }
}

// -------- finalize: exact label logit + partial sum -> per-block partial ------
// [byte-identical to R10] 256 blocks x 8 rows; wave handles 2 rows.
__global__ __launch_bounds__(256) void k_fin(const float* __restrict__ emb,
                                             const float* __restrict__ weight,
                                             const float* __restrict__ einv,
                                             const float* __restrict__ winv,
                                             const int* __restrict__ labels,
                                             const float* __restrict__ partials,
                                             float* __restrict__ finpart) {
    __shared__ float sm[8];
    int w    = threadIdx.x >> 6;       // 0..3
    int lane = threadIdx.x & 63;
    int b0   = blockIdx.x * 8 + w * 2; // wave's two rows: b0, b0+1

    int lab[2] = {labels[b0], labels[b0 + 1]};
    float4 e0[2], e1[2], w0[2], w1[2];
    float p0[2], p1[2];
    #pragma unroll
    for (int r = 0; r < 2; ++r) {      // issue all loads for both rows
        const float4* e  = (const float4*)(emb + (size_t)(b0 + r) * D_DIM);
        const float4* wt = (const float4*)(weight + (size_t)lab[r] * D_DIM);
        e0[r] = e[lane];  e1[r] = e[lane + 64];
        w0[r] = wt[lane]; w1[r] = wt[lane + 64];
        p0[r] = partials[(size_t)(b0 + r) * NCHUNK + lane];
        p1[r] = (lane + 64 < NCHUNK)
              ? partials[(size_t)(b0 + r) * NCHUNK + lane + 64] : 0.f;
    }

    #pragma unroll
    for (int r = 0; r < 2; ++r) {
        float dot = e0[r].x*w0[r].x + e0[r].y*w0[r].y + e0[r].z*w0[r].z + e0[r].w*w0[r].w
                  + e1[r].x*w1[r].x + e1[r].y*w1[r].y + e1[r].z*w1[r].z + e1[r].w*w1[r].w;
        float ls = p0[r] + p1[r];
        #pragma unroll
        for (int off = 32; off; off >>= 1) {
            dot += __shfl_xor(dot, off);
            ls  += __shfl_xor(ls, off);
        }
        if (lane == 0) {
            int b = b0 + r;
            float cosv   = dot * einv[b] * winv[lab[r]];
            float l_orig = ARC_SCALE * cosv;
            float l_adj  = ARC_SCALE * (cosv - ARC_MARGIN);
            // swap (fp8-accumulated) label term for exact margin-adjusted one
            float s_adj = ls - __expf(l_orig - ARC_SCALE) + __expf(l_adj - ARC_SCALE);
            sm[w * 2 + r] = ARC_SCALE + logf(s_adj) - l_adj;
        }
    }
    __syncthreads();
    if (threadIdx.x == 0) {
        float t = 0.f;
        #pragma unroll
        for (int i = 0; i < 8; ++i) t += sm[i];
        finpart[blockIdx.x] = t;
    }
}

// -------- k_sum: 256 block partials -> mean NLL (single block, no atomics) ----
__global__ __launch_bounds__(256) void k_sum(const float* __restrict__ finpart,
                                             float* __restrict__ out) {
    __shared__ float sm[4];
    int w = threadIdx.x >> 6, lane = threadIdx.x & 63;
    float v = finpart[threadIdx.x];
    #pragma unroll
    for (int off = 32; off; off >>= 1) v += __shfl_xor(v, off);
    if (lane == 0) sm[w] = v;
    __syncthreads();
    if (threadIdx.x == 0)
        out[0] = (sm[0] + sm[1] + sm[2] + sm[3]) * (1.0f / (float)B_ROWS);
}

extern "C" void kernel_launch(void* const* d_in, const int* in_sizes, int n_in,
                              void* d_out, int out_size, void* d_ws, size_t ws_size,
                              hipStream_t stream) {
    const float* emb    = (const float*)d_in[0];   // (2048, 512) f32
    const int*   labels = (const int*)d_in[1];     // (2048,)
    const float* weight = (const float*)d_in[2];   // (50000, 512) f32
    float* out = (float*)d_out;

    char* ws = (char*)d_ws;
    uint8_t* wq    = (uint8_t*)(ws + OFF_WQ);
    uint8_t* embq  = (uint8_t*)(ws + OFF_EMBQ);
    float* winv     = (float*)(ws + OFF_WINV);
    float* einv     = (float*)(ws + OFF_EINV);
    float* partials = (float*)(ws + OFF_PART);
    float* finpart  = (float*)(ws + OFF_FINP);

    // (C_PAD + B_ROWS) rows, 8 rows/wave, 4 waves/block
    k_prep<<<(C_PAD + B_ROWS) / 32, 256, 0, stream>>>(emb, weight, embq, wq,
                                                      einv, winv, out);

    // gemm split into two half-grid dispatches for rocprof top-5 visibility
    k_gemm<<<896, 256, 0, stream>>>(embq, wq, partials, 0);
    k_gemm<<<896, 256, 0, stream>>>(embq, wq, partials, 896);

    k_fin<<<B_ROWS / 8, 256, 0, stream>>>(emb, weight, einv, winv, labels,
                                          partials, finpart);
    k_sum<<<1, 256, 0, stream>>>(finpart, out);
}

// Round 8
// 233.698 us; speedup vs baseline: 1.1841x; 1.0442x over previous
//
#include <hip/hip_runtime.h>
#include <hip/hip_bf16.h>
#include <math.h>
#include <stdint.h>

// ArcFace loss via MX-fp8 (e4m3, identity scales) MFMA GEMM + fused
// fixed-max softmax. B=2048, D=512, C=50000. Output: scalar mean NLL (f32).
//
// R13: R12's diagnostic found the hidden mass: a 409.6MB harness poison-fill
//      (60us, fixed) + ~65us of inter-dispatch launch gaps. Kernels were
//      never the residual. So:
//      (a) gemm re-merged to ONE dispatch; k_sum folded into k_fin via the
//          R11-validated last-block ticket -> 6 dispatches become 4.
//      (b) gemm K-loop upgraded to 3-buffer counted-vmcnt pipeline (T4):
//          s_waitcnt vmcnt(4) + raw s_barrier instead of __syncthreads'
//          drain-to-0; each wave keeps the next strip's 4 loads in flight
//          across barriers. Last strip peeled with vmcnt(0).
//      prep unchanged (R10 form).
//
// Numerics: logits = 30*cos in [-30,30] -> fixed max 30, plain sums:
//   lse = 30 + log(sum_c exp(l_c - 30)); label logit recomputed exactly in
//   fp32 at finalize, so fp8 error only perturbs the softmax denominator.

#define B_ROWS    2048
#define D_DIM     512
#define C_CLASSES 50000
#define C_PAD     50176            // 112 * 448
#define NCHUNK    112              // 448-wide chunks
#define CH_COLS   448
#define NSTRIP    14               // 32-col strips per chunk
#define ARC_MARGIN 0.3f
#define ARC_SCALE  30.0f
#define ARC_EPS    1e-12f
#define K_LOG2E_S  43.2808512f     // 30 * log2(e)

// workspace layout (bytes)
#define OFF_WQ    0u               // 50176*512 = 25,690,112
#define OFF_EMBQ  25690112u        // 2048*512  =  1,048,576
#define OFF_WINV  26738688u        // 50000*4   =    200,000
#define OFF_EINV  26938688u        // 2048*4    =      8,192
#define OFF_PART  26946880u        // 2048*112*4 =   917,504
#define OFF_FINP  27864384u        // 256*4     =      1,024
#define OFF_TICK  27865408u        // 4                        -> total ~27.9 MB

typedef __attribute__((ext_vector_type(8))) int   i32x8;
typedef __attribute__((ext_vector_type(4))) int   i32x4;
typedef __attribute__((ext_vector_type(4))) float f32x4;

typedef __attribute__((address_space(1))) const unsigned int g_u32;
typedef __attribute__((address_space(3))) unsigned int       l_u32;

__device__ __forceinline__ void gload_lds16(const void* g, void* l) {
    // dest is wave-uniform LDS base; HW writes lane i at base + i*16
    g_u32* gp = (g_u32*)(uintptr_t)g;
    l_u32* lp = (l_u32*)(uintptr_t)l;
    __builtin_amdgcn_global_load_lds(gp, lp, 16, 0, 0);
}

// ---------------- prep: rows -> normalized e4m3 + inverse norms ----------------
// One wave per 8 consecutive rows; all 16 row-loads issued before any use
// (256 B/lane outstanding). Row space: [0,C_PAD) = weight (pad rows
// zero-filled), [C_PAD, C_PAD+B) = embeddings. All segments are multiples of
// 8 rows (50000, 176, 2048), so an 8-row group never straddles segments.
__global__ __launch_bounds__(256) void k_prep(const float* __restrict__ emb,
                                              const float* __restrict__ weight,
                                              uint8_t* __restrict__ embq,
                                              uint8_t* __restrict__ wq,
                                              float* __restrict__ einv,
                                              float* __restrict__ winv,
                                              unsigned int* __restrict__ ticket) {
    if (blockIdx.x == 0 && threadIdx.x == 0) *ticket = 0u;  // for k_fin last-block
    int wave = blockIdx.x * (blockDim.x >> 6) + (threadIdx.x >> 6);
    int lane = threadIdx.x & 63;
    int g0   = wave << 3;              // first of 8 consecutive rows

    const float* src;
    uint8_t* dst;
    float* invout;
    if (g0 >= C_PAD) {                 // embedding rows
        int row = g0 - C_PAD;
        src = emb + (size_t)row * D_DIM;
        dst = embq + (size_t)row * D_DIM;
        invout = einv + row;
    } else if (g0 >= C_CLASSES) {      // zero-fill pad classes
        int2 z = make_int2(0, 0);
        #pragma unroll
        for (int r = 0; r < 8; ++r)
            *(int2*)(wq + (size_t)(g0 + r) * D_DIM + lane * 8) = z;
        return;
    } else {                           // weight rows
        src = weight + (size_t)g0 * D_DIM;
        dst = wq + (size_t)g0 * D_DIM;
        invout = winv + g0;
    }

    // issue all 16 loads before any use: 256 B/lane outstanding
    const float4* r4 = (const float4*)src;
    float4 v[16];
    #pragma unroll
    for (int r = 0; r < 8; ++r) {
        v[2 * r]     = r4[r * 128 + lane * 2];
        v[2 * r + 1] = r4[r * 128 + lane * 2 + 1];
    }

    #pragma unroll
    for (int r = 0; r < 8; ++r) {
        float4 v0 = v[2 * r], v1 = v[2 * r + 1];
        float s = v0.x*v0.x + v0.y*v0.y + v0.z*v0.z + v0.w*v0.w
                + v1.x*v1.x + v1.y*v1.y + v1.z*v1.z + v1.w*v1.w;
        #pragma unroll
        for (int off = 32; off; off >>= 1) s += __shfl_xor(s, off);
        float rn = 1.0f / fmaxf(sqrtf(s), ARC_EPS);
        if (lane == 0) invout[r] = rn;
        int p0 = __builtin_amdgcn_cvt_pk_fp8_f32(v0.x * rn, v0.y * rn, 0, false);
        p0     = __builtin_amdgcn_cvt_pk_fp8_f32(v0.z * rn, v0.w * rn, p0, true);
        int p1 = __builtin_amdgcn_cvt_pk_fp8_f32(v1.x * rn, v1.y * rn, 0, false);
        p1     = __builtin_amdgcn_cvt_pk_fp8_f32(v1.z * rn, v1.w * rn, p1, true);
        *(int2*)(dst + (size_t)r * D_DIM + lane * 8) = make_int2(p0, p1);
    }
}

struct TrueT  { static constexpr bool value = true;  };
struct FalseT { static constexpr bool value = false; };

// ---------------- GEMM (MX-fp8, identity scales) + fused exp-sum -------------
// Block: 4 waves x 32 rows = 128 rows; chunk = 448 cols = 14 strips of 32.
// Wave's A rows (32 x 512B) live in regs. B strips staged in LDS, now a
// 3 x 16KB rotating buffer with counted vmcnt: per wave, the NEXT strip's 4
// gload_lds stay in flight across the barrier (s_waitcnt vmcnt(4) + raw
// s_barrier); only the peeled last strip drains to 0. WAR on the recycled
// buffer is protected by the same barrier (all waves are past compute(st-1)
// before any wave restages it).
__global__ __launch_bounds__(256) void k_gemm(const uint8_t* __restrict__ embq,
                                              const uint8_t* __restrict__ wq,
                                              float* __restrict__ partials) {
    __shared__ __align__(16) uint8_t Bs[3][16384];

    const int tid  = threadIdx.x;
    const int w    = tid >> 6;         // wave 0..3
    const int lane = tid & 63;
    const int c    = lane & 15;        // row/col within 16-group
    const int q    = lane >> 4;        // k-slice quad

    // XCD-affinity: consecutive ids round-robin XCDs; XCD x owns chunks
    // [x*14, x*14+14) for ALL row-blocks -> 3.2MB B slice stays in its L2.
    const int id  = blockIdx.x;        // 0..1791
    const int xcd = id & 7;
    const int s   = id >> 3;           // 0..223
    const int ci  = s % 14;
    const int rb  = s / 14;            // 0..15
    const int chunk = xcd * 14 + ci;
    const int b0 = rb * 128;
    const int n0 = chunk * CH_COLS;

    // ---- A fragments: wave's 32 rows, full K=512, in registers ----
    const int r0 = b0 + w * 32;
    i32x8 afA[4], afB[4];
    #pragma unroll
    for (int kt = 0; kt < 4; ++kt) {
        const uint8_t* pa = embq + (size_t)(r0 + c) * D_DIM + kt * 128 + q * 32;
        const uint8_t* pb = embq + (size_t)(r0 + 16 + c) * D_DIM + kt * 128 + q * 32;
        i32x4 alo = *(const i32x4*)pa;
        i32x4 ahi = *(const i32x4*)(pa + 16);
        i32x4 blo = *(const i32x4*)pb;
        i32x4 bhi = *(const i32x4*)(pb + 16);
        afA[kt] = (i32x8){alo[0], alo[1], alo[2], alo[3], ahi[0], ahi[1], ahi[2], ahi[3]};
        afB[kt] = (i32x8){blo[0], blo[1], blo[2], blo[3], bhi[0], bhi[1], bhi[2], bhi[3]};
    }

    // ---- staging: one 32-col x 512B strip = 16KB; 16 gload_lds16 / block,
    //      4 per wave ----
    auto stage = [&](uint8_t* dst, int st) {
        const uint8_t* base_ = wq + (size_t)(n0 + st * 32) * D_DIM;
        #pragma unroll
        for (int t = 0; t < 4; ++t) {
            const int p  = w * 4 + t;          // 0..15
            const int cb = p >> 3;             // 0..1 : 16-col group
            const int h  = p & 7;              // 0..7 : kc block of 4
            gload_lds16(base_ + (size_t)(cb * 16 + c) * D_DIM + (h * 4 + q) * 16,
                        dst + cb * 8192 + h * 1024);
        }
    };

    f32x4 rs0 = (f32x4){0.f, 0.f, 0.f, 0.f};
    f32x4 rs1 = (f32x4){0.f, 0.f, 0.f, 0.f};

    // per strip: 2 col-groups x 4 kt: bf (2 x ds_read_b128) feeds 2 MFMAs
    // (row-groups A,B); then exp2-accumulate into rs. No C-tile.
    auto compute = [&](const uint8_t* buf, int st, auto maskTag) {
        constexpr bool MASK = decltype(maskTag)::value;
        #pragma unroll
        for (int cb = 0; cb < 2; ++cb) {
            f32x4 a0 = (f32x4){0.f, 0.f, 0.f, 0.f};
            f32x4 a1 = (f32x4){0.f, 0.f, 0.f, 0.f};
            #pragma unroll
            for (int kt = 0; kt < 4; ++kt) {
                const uint8_t* p = buf + cb * 8192 + (kt * 8 + 2 * q) * 256 + c * 16;
                i32x4 lo = *(const i32x4*)p;
                i32x4 hi = *(const i32x4*)(p + 256);
                i32x8 bf = (i32x8){lo[0], lo[1], lo[2], lo[3],
                                   hi[0], hi[1], hi[2], hi[3]};
                a0 = __builtin_amdgcn_mfma_scale_f32_16x16x128_f8f6f4(
                        afA[kt], bf, a0, 0, 0, 0, 127, 0, 127);
                a1 = __builtin_amdgcn_mfma_scale_f32_16x16x128_f8f6f4(
                        afB[kt], bf, a1, 0, 0, 0, 127, 0, 127);
            }
            bool pad = false;
            if (MASK) pad = (n0 + st * 32 + cb * 16 + c) >= C_CLASSES;
            #pragma unroll
            for (int reg = 0; reg < 4; ++reg) {
                float t0 = __builtin_amdgcn_exp2f(fmaf(a0[reg], K_LOG2E_S, -K_LOG2E_S));
                float t1 = __builtin_amdgcn_exp2f(fmaf(a1[reg], K_LOG2E_S, -K_LOG2E_S));
                if (MASK && pad) { t0 = 0.f; t1 = 0.f; }
                rs0[reg] += t0;
                rs1[reg] += t1;
            }
        }
    };

    auto run = [&](auto maskTag) {
        uint8_t* p0 = &Bs[0][0];
        uint8_t* p1 = &Bs[1][0];
        uint8_t* p2 = &Bs[2][0];
        stage(p0, 0);                           // 4 loads in flight
        stage(p1, 1);                           // 8 in flight
        #pragma unroll 1
        for (int st = 0; st < NSTRIP - 1; ++st) {
            // own strip-st loads done (4 newest = strip st+1 stay in flight)
            asm volatile("s_waitcnt vmcnt(4)" ::: "memory");
            __builtin_amdgcn_s_barrier();       // all waves' st loads done;
            __builtin_amdgcn_sched_barrier(0);  // also: all past compute(st-1)
            if (st + 2 < NSTRIP) stage(p2, st + 2);   // recycle st-1's buffer
            compute(p0, st, maskTag);
            uint8_t* t = p0; p0 = p1; p1 = p2; p2 = t;
        }
        asm volatile("s_waitcnt vmcnt(0)" ::: "memory");   // peel: drain last
        __builtin_amdgcn_s_barrier();
        __builtin_amdgcn_sched_barrier(0);
        compute(p0, NSTRIP - 1, maskTag);
    };
    if (chunk == NCHUNK - 1) run(TrueT{}); else run(FalseT{});

    // wave-level col reduction: sum rs over the 16 col-lanes
    #pragma unroll
    for (int off = 1; off < 16; off <<= 1) {
        #pragma unroll
        for (int reg = 0; reg < 4; ++reg) {
            rs0[reg] += __shfl_xor(rs0[reg], off);
            rs1[reg] += __shfl_xor(rs1[reg], off);
        }
    }
    if (c == 0) {                               // lanes 0,16,32,48
        #pragma unroll
        for (int reg = 0; reg < 4; ++reg) {
            partials[(size_t)(r0 + q * 4 + reg) * NCHUNK + chunk]      = rs0[reg];
            partials[(size_t)(r0 + 16 + q * 4 + reg) * NCHUNK + chunk] = rs1[reg];
        }
    }
}

// -------- finalize: exact label logit + partial sum -> mean NLL (fused sum) ---
// 256 blocks x 8 rows; wave handles 2 rows. Block partial -> finpart[bid];
// last-arriving block (device-scope ticket, R11-validated) reduces -> out.
__global__ __launch_bounds__(256) void k_fin(const float* __restrict__ emb,
                                             const float* __restrict__ weight,
                                             const float* __restrict__ einv,
                                             const float* __restrict__ winv,
                                             const int* __restrict__ labels,
                                             const float* __restrict__ partials,
                                             float* __restrict__ finpart,
                                             unsigned int* __restrict__ ticket,
                                             float* __restrict__ out) {
    __shared__ float sm[8];
    __shared__ int is_last;
    int w    = threadIdx.x >> 6;       // 0..3
    int lane = threadIdx.x & 63;
    int b0   = blockIdx.x * 8 + w * 2; // wave's two rows: b0, b0+1

    int lab[2] = {labels[b0], labels[b0 + 1]};
    float4 e0[2], e1[2], w0[2], w1[2];
    float p0[2], p1[2];
    #pragma unroll
    for (int r = 0; r < 2; ++r) {      // issue all loads for both rows
        const float4* e  = (const float4*)(emb + (size_t)(b0 + r) * D_DIM);
        const float4* wt = (const float4*)(weight + (size_t)lab[r] * D_DIM);
        e0[r] = e[lane];  e1[r] = e[lane + 64];
        w0[r] = wt[lane]; w1[r] = wt[lane + 64];
        p0[r] = partials[(size_t)(b0 + r) * NCHUNK + lane];
        p1[r] = (lane + 64 < NCHUNK)
              ? partials[(size_t)(b0 + r) * NCHUNK + lane + 64] : 0.f;
    }

    #pragma unroll
    for (int r = 0; r < 2; ++r) {
        float dot = e0[r].x*w0[r].x + e0[r].y*w0[r].y + e0[r].z*w0[r].z + e0[r].w*w0[r].w
                  + e1[r].x*w1[r].x + e1[r].y*w1[r].y + e1[r].z*w1[r].z + e1[r].w*w1[r].w;
        float ls = p0[r] + p1[r];
        #pragma unroll
        for (int off = 32; off; off >>= 1) {
            dot += __shfl_xor(dot, off);
            ls  += __shfl_xor(ls, off);
        }
        if (lane == 0) {
            int b = b0 + r;
            float cosv   = dot * einv[b] * winv[lab[r]];
            float l_orig = ARC_SCALE * cosv;
            float l_adj  = ARC_SCALE * (cosv - ARC_MARGIN);
            // swap (fp8-accumulated) label term for exact margin-adjusted one
            float s_adj = ls - __expf(l_orig - ARC_SCALE) + __expf(l_adj - ARC_SCALE);
            sm[w * 2 + r] = ARC_SCALE + logf(s_adj) - l_adj;
        }
    }
    __syncthreads();
    if (threadIdx.x == 0) {
        float t = 0.f;
        #pragma unroll
        for (int i = 0; i < 8; ++i) t += sm[i];
        finpart[blockIdx.x] = t;
        __threadfence();                               // publish before ticket
        unsigned int old = atomicAdd(ticket, 1u);      // device scope
        is_last = (old == gridDim.x - 1) ? 1 : 0;
    }
    __syncthreads();
    if (is_last) {
        __threadfence();                               // acquire finpart
        volatile const float* fp = finpart;
        float v = fp[threadIdx.x];
        #pragma unroll
        for (int off = 32; off; off >>= 1) v += __shfl_xor(v, off);
        if (lane == 0) sm[w] = v;
        __syncthreads();
        if (threadIdx.x == 0)
            out[0] = (sm[0] + sm[1] + sm[2] + sm[3]) * (1.0f / (float)B_ROWS);
    }
}

extern "C" void kernel_launch(void* const* d_in, const int* in_sizes, int n_in,
                              void* d_out, int out_size, void* d_ws, size_t ws_size,
                              hipStream_t stream) {
    const float* emb    = (const float*)d_in[0];   // (2048, 512) f32
    const int*   labels = (const int*)d_in[1];     // (2048,)
    const float* weight = (const float*)d_in[2];   // (50000, 512) f32
    float* out = (float*)d_out;

    char* ws = (char*)d_ws;
    uint8_t* wq    = (uint8_t*)(ws + OFF_WQ);
    uint8_t* embq  = (uint8_t*)(ws + OFF_EMBQ);
    float* winv     = (float*)(ws + OFF_WINV);
    float* einv     = (float*)(ws + OFF_EINV);
    float* partials = (float*)(ws + OFF_PART);
    float* finpart  = (float*)(ws + OFF_FINP);
    unsigned int* ticket = (unsigned int*)(ws + OFF_TICK);

    // (C_PAD + B_ROWS) rows, 8 rows/wave, 4 waves/block
    k_prep<<<(C_PAD + B_ROWS) / 32, 256, 0, stream>>>(emb, weight, embq, wq,
                                                      einv, winv, ticket);

    // 8 XCD x (14 chunks x 16 row-blocks) = 1792 blocks
    k_gemm<<<1792, 256, 0, stream>>>(embq, wq, partials);

    k_fin<<<B_ROWS / 8, 256, 0, stream>>>(emb, weight, einv, winv, labels,
                                          partials, finpart, ticket, out);
}